// Round 5
// baseline (34.039 us; speedup 1.0000x reference)
//
#include <hip/hip_runtime.h>
#include <stdint.h>

#define BATCH 16384
#define KDIM  512
#define NDIM  1024
#define NW    16            // 512 bits = 16 uint32 words per row
#define THREADS 512         // 8 waves; each thread owns 2 adjacent columns
#define ROWS_PER_BLOCK 16   // 1024 blocks
#define PHASE_ROWS 4        // one float4/thread = 4 rows per phase
#define NPHASE (ROWS_PER_BLOCK / PHASE_ROWS)

typedef float f32x4 __attribute__((ext_vector_type(4)));
typedef int   i32x2 __attribute__((ext_vector_type(2)));

// --- G packing v2: 512 blocks, 8 threads per word (4 bits each), LDS combine.
// Bit mapping UNCHANGED (verified rounds 2-4): bit c of word (m,n) is
// G[kbase(m) + 4c, n] with kbase = 256*(m>>3) + 128*((m>>2)&1) + (m&3).
__global__ __launch_bounds__(256) void pack_g_kernel(const float* __restrict__ G,
                                                     uint32_t* __restrict__ Gt) {
    __shared__ uint32_t nib[8][32];
    const int bid = blockIdx.x;          // 512 blocks
    const int m   = bid >> 5;            // 0..15
    const int n0  = (bid & 31) << 5;     // column chunk base
    const int tid = threadIdx.x;
    const int p   = tid >> 5;            // piece 0..7 (bits 4p..4p+3)
    const int nn  = tid & 31;
    const int n   = n0 + nn;
    const int kbase = 256 * (m >> 3) + 128 * ((m >> 2) & 1) + (m & 3);
    uint32_t w = 0;
#pragma unroll
    for (int j = 0; j < 4; ++j) {
        int c = 4 * p + j;
        w |= (uint32_t)(G[(size_t)(kbase + 4 * c) * NDIM + n] > 0.5f) << c;
    }
    nib[p][nn] = w;
    __syncthreads();
    if (tid < 32) {
        uint32_t r = nib[0][tid] | nib[1][tid] | nib[2][tid] | nib[3][tid]
                   | nib[4][tid] | nib[5][tid] | nib[6][tid] | nib[7][tid];
        Gt[m * NDIM + n0 + tid] = r;
    }
}

// --- fused pack(x) + GF(2) GEMM, 2 columns/thread, non-temporal streams ---
// Structure identical to round 4 (verified absmax 0); x loads and out stores
// are now non-temporal (read-once / write-once, no reuse -> bypass L2).
__global__ __launch_bounds__(THREADS, 6)
void gf2_fused_kernel(const float* __restrict__ x,
                      const uint32_t* __restrict__ Gt,
                      int* __restrict__ out) {
    const int tid = threadIdx.x;
    const int w   = tid >> 6;     // wave 0..7
    const int l   = tid & 63;     // lane
    const int q   = w >> 1;       // row within phase (0..3)
    const int h   = w & 1;        // k-half (0: k<256, 1: k>=256)
    const int row0 = blockIdx.x * ROWS_PER_BLOCK;

    // persistent column fragments: cols 2*tid, 2*tid+1 (coalesced uint2 loads)
    uint32_t g0[NW], g1[NW];
#pragma unroll
    for (int m = 0; m < NW; ++m) {
        uint2 gg = reinterpret_cast<const uint2*>(Gt + m * NDIM)[tid];
        g0[m] = gg.x;
        g1[m] = gg.y;
    }

    __shared__ __align__(16) uint32_t xw[2][PHASE_ROWS][NW];   // 2 x 256 B

    const f32x4* xf = reinterpret_cast<const f32x4*>(x);
    f32x4 f = __builtin_nontemporal_load(xf + (size_t)row0 * (KDIM / 4) + tid);

    for (int p = 0; p < NPHASE; ++p) {
        // ---- ballot-pack 4 rows (consumes f) ----
        uint64_t b0 = __ballot(f.x > 0.5f);
        uint64_t b1 = __ballot(f.y > 0.5f);
        uint64_t b2 = __ballot(f.z > 0.5f);
        uint64_t b3 = __ballot(f.w > 0.5f);

        // prefetch next phase's slab (hidden under compute below)
        if (p + 1 < NPHASE)
            f = __builtin_nontemporal_load(
                    xf + (size_t)(row0 + (p + 1) * PHASE_ROWS) * (KDIM / 4) + tid);

        if (l == 0) {
            uint32_t* dst = &xw[p & 1][q][h * 8];
            dst[0] = (uint32_t)b0;  dst[4] = (uint32_t)(b0 >> 32);
            dst[1] = (uint32_t)b1;  dst[5] = (uint32_t)(b1 >> 32);
            dst[2] = (uint32_t)b2;  dst[6] = (uint32_t)(b2 >> 32);
            dst[3] = (uint32_t)b3;  dst[7] = (uint32_t)(b3 >> 32);
        }
        __syncthreads();   // double-buffer: one barrier per phase is race-free

        // ---- compute 4 rows x 2 columns ----
        size_t obase = (size_t)(row0 + p * PHASE_ROWS) * NDIM + 2 * (size_t)tid;
#pragma unroll
        for (int r = 0; r < PHASE_ROWS; ++r) {
            const uint4* x4 = reinterpret_cast<const uint4*>(&xw[p & 1][r][0]);
            uint4 a0 = x4[0], a1 = x4[1], a2 = x4[2], a3 = x4[3];
            uint32_t t0 = (a0.x & g0[0])  ^ (a0.y & g0[1])  ^ (a0.z & g0[2])  ^ (a0.w & g0[3])
                        ^ (a1.x & g0[4])  ^ (a1.y & g0[5])  ^ (a1.z & g0[6])  ^ (a1.w & g0[7])
                        ^ (a2.x & g0[8])  ^ (a2.y & g0[9])  ^ (a2.z & g0[10]) ^ (a2.w & g0[11])
                        ^ (a3.x & g0[12]) ^ (a3.y & g0[13]) ^ (a3.z & g0[14]) ^ (a3.w & g0[15]);
            uint32_t t1 = (a0.x & g1[0])  ^ (a0.y & g1[1])  ^ (a0.z & g1[2])  ^ (a0.w & g1[3])
                        ^ (a1.x & g1[4])  ^ (a1.y & g1[5])  ^ (a1.z & g1[6])  ^ (a1.w & g1[7])
                        ^ (a2.x & g1[8])  ^ (a2.y & g1[9])  ^ (a2.z & g1[10]) ^ (a2.w & g1[11])
                        ^ (a3.x & g1[12]) ^ (a3.y & g1[13]) ^ (a3.z & g1[14]) ^ (a3.w & g1[15]);
            i32x2 o;
            o.x = (int)(__popc(t0) & 1u);
            o.y = (int)(__popc(t1) & 1u);
            __builtin_nontemporal_store(
                o, reinterpret_cast<i32x2*>(out + obase + (size_t)r * NDIM));
        }
    }
}

extern "C" void kernel_launch(void* const* d_in, const int* in_sizes, int n_in,
                              void* d_out, int out_size, void* d_ws, size_t ws_size,
                              hipStream_t stream) {
    const float* x = (const float*)d_in[0];   // [BATCH, KDIM] float32 (0/1)
    const float* G = (const float*)d_in[1];   // [KDIM, NDIM] float32 (0/1)
    int* out = (int*)d_out;                   // [BATCH, NDIM] int32

    uint32_t* Gt = (uint32_t*)d_ws;           // 64 KiB packed G

    pack_g_kernel<<<512, 256, 0, stream>>>(G, Gt);
    gf2_fused_kernel<<<BATCH / ROWS_PER_BLOCK, THREADS, 0, stream>>>(x, Gt, out);
}

// Round 6
// 30.231 us; speedup vs baseline: 1.1260x; 1.1260x over previous
//
#include <hip/hip_runtime.h>
#include <stdint.h>

#define BATCH 16384
#define KDIM  512
#define NDIM  1024
#define NW    16            // 512 bits = 16 uint32 words per K-row

typedef int i32x2 __attribute__((ext_vector_type(2)));

// --- Kernel A: pack x AND G in one launch ---
// Blocks 0..1023: pack x. Thread -> one xp word (plain order):
//   xp[b*16 + i] bit j = x[b, 32i + j]
// Blocks 1024..1535: pack G (8 threads/word, 4 bits each, LDS-combine):
//   Gt[m*NDIM + n] bit c = G[32m + c, n]
__global__ __launch_bounds__(256) void pack_kernel(const float* __restrict__ x,
                                                   const float* __restrict__ G,
                                                   uint32_t* __restrict__ xp,
                                                   uint32_t* __restrict__ Gt) {
    const int bid = blockIdx.x;
    if (bid < 1024) {
        int t = bid * 256 + threadIdx.x;      // global word index, 0..262143
        const float4* xf = reinterpret_cast<const float4*>(x) + (size_t)t * 8;
        uint32_t w = 0;
#pragma unroll
        for (int u = 0; u < 8; ++u) {
            float4 f = xf[u];
            w |= (uint32_t)(f.x > 0.5f) << (4 * u + 0);
            w |= (uint32_t)(f.y > 0.5f) << (4 * u + 1);
            w |= (uint32_t)(f.z > 0.5f) << (4 * u + 2);
            w |= (uint32_t)(f.w > 0.5f) << (4 * u + 3);
        }
        xp[t] = w;
    } else {
        __shared__ uint32_t nib[8][32];
        const int b  = bid - 1024;            // 0..511
        const int m  = b >> 5;                // word index 0..15
        const int n0 = (b & 31) << 5;         // column chunk base
        const int p  = threadIdx.x >> 5;      // piece 0..7 (bits 4p..4p+3)
        const int nn = threadIdx.x & 31;
        uint32_t w = 0;
#pragma unroll
        for (int j = 0; j < 4; ++j) {
            int c = 4 * p + j;
            w |= (uint32_t)(G[(size_t)(m * 32 + c) * NDIM + n0 + nn] > 0.5f) << c;
        }
        nib[p][nn] = w;
        __syncthreads();
        if (threadIdx.x < 32) {
            uint32_t r = nib[0][threadIdx.x] | nib[1][threadIdx.x]
                       | nib[2][threadIdx.x] | nib[3][threadIdx.x]
                       | nib[4][threadIdx.x] | nib[5][threadIdx.x]
                       | nib[6][threadIdx.x] | nib[7][threadIdx.x];
            Gt[m * NDIM + n0 + threadIdx.x] = r;
        }
    }
}

// --- Kernel B: GF(2) GEMM from packed operands; pure-write streaming ---
// 512 threads, 2 adjacent cols/thread (g = 32 VGPRs), 32 rows/block.
// Row words are wave-uniform loads (scalarizable, broadcast) -> no LDS,
// no ballots, no barriers. out[b,n] = popc(XOR_i (xp[b,i] & Gt[i,n])) & 1.
#define BROWS 32
__global__ __launch_bounds__(512, 4)
void gf2_gemm_kernel(const uint32_t* __restrict__ xp,
                     const uint32_t* __restrict__ Gt,
                     int* __restrict__ out) {
    const int tid = threadIdx.x;

    uint32_t g0[NW], g1[NW];
#pragma unroll
    for (int i = 0; i < NW; ++i) {
        uint2 gg = reinterpret_cast<const uint2*>(Gt + i * NDIM)[tid];
        g0[i] = gg.x;
        g1[i] = gg.y;
    }

    const int row0 = blockIdx.x * BROWS;
#pragma unroll 4
    for (int r = 0; r < BROWS; ++r) {
        const uint4* xr = reinterpret_cast<const uint4*>(xp + (size_t)(row0 + r) * NW);
        uint4 xa = xr[0], xb = xr[1], xc = xr[2], xd = xr[3];   // block-uniform
        uint32_t t0 = (xa.x & g0[0])  ^ (xa.y & g0[1])  ^ (xa.z & g0[2])  ^ (xa.w & g0[3])
                    ^ (xb.x & g0[4])  ^ (xb.y & g0[5])  ^ (xb.z & g0[6])  ^ (xb.w & g0[7])
                    ^ (xc.x & g0[8])  ^ (xc.y & g0[9])  ^ (xc.z & g0[10]) ^ (xc.w & g0[11])
                    ^ (xd.x & g0[12]) ^ (xd.y & g0[13]) ^ (xd.z & g0[14]) ^ (xd.w & g0[15]);
        uint32_t t1 = (xa.x & g1[0])  ^ (xa.y & g1[1])  ^ (xa.z & g1[2])  ^ (xa.w & g1[3])
                    ^ (xb.x & g1[4])  ^ (xb.y & g1[5])  ^ (xb.z & g1[6])  ^ (xb.w & g1[7])
                    ^ (xc.x & g1[8])  ^ (xc.y & g1[9])  ^ (xc.z & g1[10]) ^ (xc.w & g1[11])
                    ^ (xd.x & g1[12]) ^ (xd.y & g1[13]) ^ (xd.z & g1[14]) ^ (xd.w & g1[15]);
        i32x2 o;
        o.x = (int)(__popc(t0) & 1u);
        o.y = (int)(__popc(t1) & 1u);
        *reinterpret_cast<i32x2*>(out + (size_t)(row0 + r) * NDIM + 2 * (size_t)tid) = o;
    }
}

extern "C" void kernel_launch(void* const* d_in, const int* in_sizes, int n_in,
                              void* d_out, int out_size, void* d_ws, size_t ws_size,
                              hipStream_t stream) {
    const float* x = (const float*)d_in[0];   // [BATCH, KDIM] float32 (0/1)
    const float* G = (const float*)d_in[1];   // [KDIM, NDIM] float32 (0/1)
    int* out = (int*)d_out;                   // [BATCH, NDIM] int32

    // workspace: xp (1 MiB) then Gt (64 KiB)
    uint32_t* xp = (uint32_t*)d_ws;
    uint32_t* Gt = (uint32_t*)((char*)d_ws + (size_t)BATCH * NW * 4);

    pack_kernel<<<1024 + 512, 256, 0, stream>>>(x, G, xp, Gt);
    gf2_gemm_kernel<<<BATCH / BROWS, 512, 0, stream>>>(xp, Gt, out);
}

// Round 7
// 27.782 us; speedup vs baseline: 1.2252x; 1.0882x over previous
//
#include <hip/hip_runtime.h>
#include <stdint.h>

#define BATCH 16384
#define KDIM  512
#define NDIM  1024
#define NW    16            // 512 bits = 16 uint32 words per row
#define THREADS 512         // 8 waves; each thread owns 2 adjacent columns
#define ROWS_PER_BLOCK 16   // 1024 blocks
#define PHASE_ROWS 4        // one float4/thread = 4 rows per phase
#define NPHASE (ROWS_PER_BLOCK / PHASE_ROWS)

typedef int i32x2 __attribute__((ext_vector_type(2)));

// --- G packing: 512 blocks, 8 threads per word (4 bits each), LDS combine.
// Bit mapping (verified rounds 2-5): bit c of word (m,n) is
// G[kbase(m) + 4c, n] with kbase = 256*(m>>3) + 128*((m>>2)&1) + (m&3).
__global__ __launch_bounds__(256) void pack_g_kernel(const float* __restrict__ G,
                                                     uint32_t* __restrict__ Gt) {
    __shared__ uint32_t nib[8][32];
    const int bid = blockIdx.x;          // 512 blocks
    const int m   = bid >> 5;            // 0..15
    const int n0  = (bid & 31) << 5;     // column chunk base
    const int tid = threadIdx.x;
    const int p   = tid >> 5;            // piece 0..7 (bits 4p..4p+3)
    const int nn  = tid & 31;
    const int n   = n0 + nn;
    const int kbase = 256 * (m >> 3) + 128 * ((m >> 2) & 1) + (m & 3);
    uint32_t w = 0;
#pragma unroll
    for (int j = 0; j < 4; ++j) {
        int c = 4 * p + j;
        w |= (uint32_t)(G[(size_t)(kbase + 4 * c) * NDIM + n] > 0.5f) << c;
    }
    nib[p][nn] = w;
    __syncthreads();
    if (tid < 32) {
        uint32_t r = nib[0][tid] | nib[1][tid] | nib[2][tid] | nib[3][tid]
                   | nib[4][tid] | nib[5][tid] | nib[6][tid] | nib[7][tid];
        Gt[m * NDIM + n0 + tid] = r;
    }
}

// --- fused pack(x) + GF(2) GEMM, 2 columns/thread ---
// Identical to round 4 (verified absmax 0) EXCEPT: the phase barrier is a raw
// s_barrier with only lgkmcnt(0) (LDS visibility). __syncthreads would emit
// s_waitcnt vmcnt(0) and drain the output-store stream every phase; with the
// raw barrier, stores and the x prefetch stay in flight across phases.
__global__ __launch_bounds__(THREADS, 6)
void gf2_fused_kernel(const float* __restrict__ x,
                      const uint32_t* __restrict__ Gt,
                      int* __restrict__ out) {
    const int tid = threadIdx.x;
    const int w   = tid >> 6;     // wave 0..7
    const int l   = tid & 63;     // lane
    const int q   = w >> 1;       // row within phase (0..3)
    const int h   = w & 1;        // k-half (0: k<256, 1: k>=256)
    const int row0 = blockIdx.x * ROWS_PER_BLOCK;

    // persistent column fragments: cols 2*tid, 2*tid+1 (coalesced uint2 loads)
    uint32_t g0[NW], g1[NW];
#pragma unroll
    for (int m = 0; m < NW; ++m) {
        uint2 gg = reinterpret_cast<const uint2*>(Gt + m * NDIM)[tid];
        g0[m] = gg.x;
        g1[m] = gg.y;
    }

    __shared__ __align__(16) uint32_t xw[2][PHASE_ROWS][NW];   // 2 x 256 B

    const float4* xf = reinterpret_cast<const float4*>(x);
    float4 f = xf[(size_t)row0 * (KDIM / 4) + tid];            // phase-0 slab

    for (int p = 0; p < NPHASE; ++p) {
        // ---- ballot-pack 4 rows (consumes f) ----
        uint64_t b0 = __ballot(f.x > 0.5f);
        uint64_t b1 = __ballot(f.y > 0.5f);
        uint64_t b2 = __ballot(f.z > 0.5f);
        uint64_t b3 = __ballot(f.w > 0.5f);

        // prefetch next phase's slab (stays in flight across the raw barrier)
        if (p + 1 < NPHASE)
            f = xf[(size_t)(row0 + (p + 1) * PHASE_ROWS) * (KDIM / 4) + tid];

        if (l == 0) {
            uint32_t* dst = &xw[p & 1][q][h * 8];
            dst[0] = (uint32_t)b0;  dst[4] = (uint32_t)(b0 >> 32);
            dst[1] = (uint32_t)b1;  dst[5] = (uint32_t)(b1 >> 32);
            dst[2] = (uint32_t)b2;  dst[6] = (uint32_t)(b2 >> 32);
            dst[3] = (uint32_t)b3;  dst[7] = (uint32_t)(b3 >> 32);
        }
        // Raw barrier: wait ONLY for LDS ops (writer's ds_writes visible),
        // do NOT drain vmcnt (output stores / x prefetch keep flowing).
        // Memory-clobber fences pin ds ops on the correct side (rule 18).
        asm volatile("s_waitcnt lgkmcnt(0)" ::: "memory");
        __builtin_amdgcn_s_barrier();
        asm volatile("" ::: "memory");

        // ---- compute 4 rows x 2 columns ----
        size_t obase = (size_t)(row0 + p * PHASE_ROWS) * NDIM + 2 * (size_t)tid;
#pragma unroll
        for (int r = 0; r < PHASE_ROWS; ++r) {
            const uint4* x4 = reinterpret_cast<const uint4*>(&xw[p & 1][r][0]);
            uint4 a0 = x4[0], a1 = x4[1], a2 = x4[2], a3 = x4[3];
            uint32_t t0 = (a0.x & g0[0])  ^ (a0.y & g0[1])  ^ (a0.z & g0[2])  ^ (a0.w & g0[3])
                        ^ (a1.x & g0[4])  ^ (a1.y & g0[5])  ^ (a1.z & g0[6])  ^ (a1.w & g0[7])
                        ^ (a2.x & g0[8])  ^ (a2.y & g0[9])  ^ (a2.z & g0[10]) ^ (a2.w & g0[11])
                        ^ (a3.x & g0[12]) ^ (a3.y & g0[13]) ^ (a3.z & g0[14]) ^ (a3.w & g0[15]);
            uint32_t t1 = (a0.x & g1[0])  ^ (a0.y & g1[1])  ^ (a0.z & g1[2])  ^ (a0.w & g1[3])
                        ^ (a1.x & g1[4])  ^ (a1.y & g1[5])  ^ (a1.z & g1[6])  ^ (a1.w & g1[7])
                        ^ (a2.x & g1[8])  ^ (a2.y & g1[9])  ^ (a2.z & g1[10]) ^ (a2.w & g1[11])
                        ^ (a3.x & g1[12]) ^ (a3.y & g1[13]) ^ (a3.z & g1[14]) ^ (a3.w & g1[15]);
            i32x2 o;
            o.x = (int)(__popc(t0) & 1u);
            o.y = (int)(__popc(t1) & 1u);
            *reinterpret_cast<i32x2*>(out + obase + (size_t)r * NDIM) = o;
        }
        // No trailing barrier needed: the next phase's single barrier
        // separates this phase's reads of buf[p&1] from its overwrite at p+2.
    }
}

extern "C" void kernel_launch(void* const* d_in, const int* in_sizes, int n_in,
                              void* d_out, int out_size, void* d_ws, size_t ws_size,
                              hipStream_t stream) {
    const float* x = (const float*)d_in[0];   // [BATCH, KDIM] float32 (0/1)
    const float* G = (const float*)d_in[1];   // [KDIM, NDIM] float32 (0/1)
    int* out = (int*)d_out;                   // [BATCH, NDIM] int32

    uint32_t* Gt = (uint32_t*)d_ws;           // 64 KiB packed G

    pack_g_kernel<<<512, 256, 0, stream>>>(G, Gt);
    gf2_fused_kernel<<<BATCH / ROWS_PER_BLOCK, THREADS, 0, stream>>>(x, Gt, out);
}